// Round 10
// baseline (805.140 us; speedup 1.0000x reference)
//
#include <hip/hip_runtime.h>

#define BB 256
#define TT 2048
#define NN 64
#define CHK 512

// DPP row-rotate (within each 16-lane row). K compile-time.
template <int K>
__device__ __forceinline__ int dpp_ror_i(int v) {
  return __builtin_amdgcn_update_dpp(0, v, 0x120 | K, 0xF, 0xF, true);
}
template <int K>
__device__ __forceinline__ float dpp_ror_f(float v) {
  return __int_as_float(dpp_ror_i<K>(__float_as_int(v)));
}

// Cross-row combines via gfx950 permlane swaps (pure VALU, no DS pipe).
// With b = a, the swap leaves a/b holding the two paired-row copies in every
// lane, so fmax/min(a,b) = per-lane combine of row q with q^1 (16-swap) or
// q with q^2 (32-swap) -- result valid in ALL lanes.
__device__ __forceinline__ float rowpair_max(float m) {
  int a = __float_as_int(m), b = a;
  asm volatile("v_permlane16_swap_b32 %0, %1" : "+v"(a), "+v"(b));
  float fa = __int_as_float(a), fb = __int_as_float(b);
  return fmaxf(fa, fb);
}
__device__ __forceinline__ float half_max(float m) {
  int a = __float_as_int(m), b = a;
  asm volatile("v_permlane32_swap_b32 %0, %1" : "+v"(a), "+v"(b));
  float fa = __int_as_float(a), fb = __int_as_float(b);
  return fmaxf(fa, fb);
}
__device__ __forceinline__ int rowpair_min(int v) {
  int a = v, b = v;
  asm volatile("v_permlane16_swap_b32 %0, %1" : "+v"(a), "+v"(b));
  return a < b ? a : b;
}
__device__ __forceinline__ int half_min(int v) {
  int a = v, b = v;
  asm volatile("v_permlane32_swap_b32 %0, %1" : "+v"(a), "+v"(b));
  return a < b ? a : b;
}

__global__ __launch_bounds__(256, 1)
void crf_viterbi_kernel(const float* __restrict__ x,
                        const int* __restrict__ seq_len,
                        const float* __restrict__ trans,
                        float* __restrict__ out) {
  const int b = blockIdx.x;
  const int tid = threadIdx.x;
  const int lane = tid & 63;
  const int w = tid >> 6;       // wave id 0..3
  const int c = lane & 15;      // column within wave's 16
  const int jc = (w << 4) + c;  // global output column this lane serves
                                // row q = lane>>4 = i-quarter (implicit)

  __shared__ __align__(16) float alpha_s[2][NN];
  __shared__ unsigned char bp_s[(TT - 1) * NN];  // 131008 B backpointers
  __shared__ int map_s[4][NN];                   // chunk traceback maps

  const float* xb = x + (size_t)b * TT * NN;
  const int slen = seq_len[b];

  // Rotation-source indices, derived with the SAME DPP as alpha (direction-
  // proof): idxv[k] = the i whose alpha lands in this lane under rotation k.
  int idxv[16];
  idxv[0] = lane;
  idxv[1] = dpp_ror_i<1>(lane);   idxv[2] = dpp_ror_i<2>(lane);
  idxv[3] = dpp_ror_i<3>(lane);   idxv[4] = dpp_ror_i<4>(lane);
  idxv[5] = dpp_ror_i<5>(lane);   idxv[6] = dpp_ror_i<6>(lane);
  idxv[7] = dpp_ror_i<7>(lane);   idxv[8] = dpp_ror_i<8>(lane);
  idxv[9] = dpp_ror_i<9>(lane);   idxv[10] = dpp_ror_i<10>(lane);
  idxv[11] = dpp_ror_i<11>(lane); idxv[12] = dpp_ror_i<12>(lane);
  idxv[13] = dpp_ror_i<13>(lane); idxv[14] = dpp_ror_i<14>(lane);
  idxv[15] = dpp_ror_i<15>(lane);

  float tcv[16];
#pragma unroll
  for (int k = 0; k < 16; ++k) tcv[k] = trans[idxv[k] * NN + jc];

  if (w == 0) alpha_s[0][lane] = xb[lane];
  __syncthreads();

  // 2-deep x prefetch; raw barriers below never drain vmcnt.
  float xn1 = xb[NN + jc];
  float xn2 = xb[2 * NN + jc];

  for (int t = 1; t < slen; ++t) {
    float xv = xn1;
    xn1 = xn2;
    {
      int tn = (t + 2 < TT) ? (t + 2) : (TT - 1);
      xn2 = xb[(size_t)tn * NN + jc];
    }
    const int pr = (t + 1) & 1;  // read parity (t=1 reads buf 0)
    const int pw = t & 1;        // write parity

    float av = alpha_s[pr][lane];

    // 16 candidates via DPP rotations (all depend only on av; issue-limited)
    float c0 = av + tcv[0];
    float c1 = dpp_ror_f<1>(av) + tcv[1];
    float c2 = dpp_ror_f<2>(av) + tcv[2];
    float c3 = dpp_ror_f<3>(av) + tcv[3];
    float c4 = dpp_ror_f<4>(av) + tcv[4];
    float c5 = dpp_ror_f<5>(av) + tcv[5];
    float c6 = dpp_ror_f<6>(av) + tcv[6];
    float c7 = dpp_ror_f<7>(av) + tcv[7];
    float c8 = dpp_ror_f<8>(av) + tcv[8];
    float c9 = dpp_ror_f<9>(av) + tcv[9];
    float c10 = dpp_ror_f<10>(av) + tcv[10];
    float c11 = dpp_ror_f<11>(av) + tcv[11];
    float c12 = dpp_ror_f<12>(av) + tcv[12];
    float c13 = dpp_ror_f<13>(av) + tcv[13];
    float c14 = dpp_ror_f<14>(av) + tcv[14];
    float c15 = dpp_ror_f<15>(av) + tcv[15];

    // value max: balanced fmax tree (fuses to v_max3), then VALU row combines
    float m = fmaxf(fmaxf(fmaxf(fmaxf(c0, c1), fmaxf(c2, c3)),
                          fmaxf(fmaxf(c4, c5), fmaxf(c6, c7))),
                    fmaxf(fmaxf(fmaxf(c8, c9), fmaxf(c10, c11)),
                          fmaxf(fmaxf(c12, c13), fmaxf(c14, c15))));
    m = rowpair_max(m);
    m = half_max(m);

    // first-occurrence argmax = MIN index achieving the (exact) max
    int s0 = (c0 == m) ? idxv[0] : NN;
    int s1 = (c1 == m) ? idxv[1] : NN;
    int s2 = (c2 == m) ? idxv[2] : NN;
    int s3 = (c3 == m) ? idxv[3] : NN;
    int s4 = (c4 == m) ? idxv[4] : NN;
    int s5 = (c5 == m) ? idxv[5] : NN;
    int s6 = (c6 == m) ? idxv[6] : NN;
    int s7 = (c7 == m) ? idxv[7] : NN;
    int s8 = (c8 == m) ? idxv[8] : NN;
    int s9 = (c9 == m) ? idxv[9] : NN;
    int s10 = (c10 == m) ? idxv[10] : NN;
    int s11 = (c11 == m) ? idxv[11] : NN;
    int s12 = (c12 == m) ? idxv[12] : NN;
    int s13 = (c13 == m) ? idxv[13] : NN;
    int s14 = (c14 == m) ? idxv[14] : NN;
    int s15 = (c15 == m) ? idxv[15] : NN;
    int idx = min(min(min(min(s0, s1), min(s2, s3)),
                      min(min(s4, s5), min(s6, s7))),
                  min(min(min(s8, s9), min(s10, s11)),
                      min(min(s12, s13), min(s14, s15))));
    idx = rowpair_min(idx);
    idx = half_min(idx);

    // row-0 lanes publish alpha & bp for this wave's 16 columns
    if (lane < 16) {
      alpha_s[pw][jc] = m + xv;
      bp_s[(t - 1) * NN + jc] = (unsigned char)idx;
    }
    // raw barrier WITHOUT vmcnt drain: LDS ordered, prefetch stays in flight
    asm volatile("s_waitcnt lgkmcnt(0)\n\ts_barrier" ::: "memory");
  }

  // final argmax over states (exact; smaller index wins ties)
  const int pf = (slen - 1) & 1;
  float best = alpha_s[pf][lane];
  int last = lane;
#pragma unroll
  for (int mask = 1; mask < 64; mask <<= 1) {
    float ov = __shfl_xor(best, mask, 64);
    int oi = __shfl_xor(last, mask, 64);
    bool take = (ov > best) || (ov == best && oi < last);
    best = take ? ov : best;
    last = take ? oi : last;
  }
  const float lastf = (float)last;
  const int bTT = b * TT;

  // tags[t] = last for all t >= slen-1 (identity region), coalesced
  for (int t = slen - 1 + tid; t < TT; t += 256) out[bTT + t] = lastf;
  if (tid == 0) out[BB * TT + b] = best;  // scores: exact fp32

  // ---- parallel traceback ----
  // Phase A: lane e of wave w composes chunk w's bp map from every state.
  // map_s[0] is never used -> wave 0 skips (less DS traffic).
  const int lo = CHK * w;
  const int hi = ((CHK * (w + 1) - 1) < (slen - 2)) ? (CHK * (w + 1) - 1)
                                                    : (slen - 2);
  if (w > 0) {
    int s = lane;
    for (int r = hi; r >= lo; --r) s = bp_s[r * NN + s];
    map_s[w][lane] = s;
  }
  __syncthreads();

  // Fold maps (redundant in every thread): entry state per chunk.
  const int e3 = last;
  const int e2 = map_s[3][e3];
  const int e1 = map_s[2][e2];
  const int e0 = map_s[1][e1];
  const int entry = (w == 3) ? e3 : (w == 2) ? e2 : (w == 1) ? e1 : e0;

  // Phase B: one lane per wave re-traces its chunk writing tags.
  if (lane == 0) {
    int s = entry;
    for (int r = hi; r >= lo; --r) {
      s = bp_s[r * NN + s];
      out[bTT + r] = (float)s;
    }
  }
}

extern "C" void kernel_launch(void* const* d_in, const int* in_sizes, int n_in,
                              void* d_out, int out_size, void* d_ws, size_t ws_size,
                              hipStream_t stream) {
  const float* x = (const float*)d_in[0];
  const int* seq_len = (const int*)d_in[1];
  const float* trans = (const float*)d_in[2];
  float* out = (float*)d_out;

  crf_viterbi_kernel<<<BB, 256, 0, stream>>>(x, seq_len, trans, out);
}